// Round 12
// baseline (99.674 us; speedup 1.0000x reference)
//
#include <hip/hip_runtime.h>

#define T_LEN 512
#define LOG2E 1.4426950408889634f

typedef float f32x2 __attribute__((ext_vector_type(2)));

// v11: 4 batches/wave, 16 lanes/batch (group g = lane>>4). Lane j = lane&15
// owns ALL FOUR gate rows of hidden index j: rows j, 16+j, 32+j, 48+j.
//  - gates are lane-local: no cross-lane gather for i,f,g,o
//  - h broadcast = 15x v_mov_b32_dpp row_ror:r (VALU, within the 16-lane row
//    = within the batch) + 1 plain mov; slot r on lane j holds h_{(j-r)&15},
//    compensated by a per-lane PERMUTED weight preload -> matvec unchanged.
//  - only DS op per step: one x broadcast read (double-buffered, lgkmcnt(1)).
// Weights prescaled by the activation constant (-log2e / -2log2e) so the
// matvec result feeds v_exp directly. All state (c, h, slots) in registers.
// LDS per batch: [x 512][hf 16][hb 16] = 544 floats.
__global__ __launch_bounds__(128, 1) void bilstm_head_kernel(
    const float* __restrict__ x,
    const float* __restrict__ W_ih_f, const float* __restrict__ W_hh_f,
    const float* __restrict__ b_ih_f, const float* __restrict__ b_hh_f,
    const float* __restrict__ W_ih_r, const float* __restrict__ W_hh_r,
    const float* __restrict__ b_ih_r, const float* __restrict__ b_hh_r,
    const float* __restrict__ W1, const float* __restrict__ b1,
    const float* __restrict__ W2, const float* __restrict__ b2,
    float* __restrict__ out)
{
    extern __shared__ float smem[];          // 8 regions * 544 floats

    const int tid   = threadIdx.x;
    const int wid   = tid >> 6;              // 0..1
    const int lane  = tid & 63;
    const int g     = (lane >> 4) & 3;       // batch group within wave
    const int j     = lane & 15;             // hidden index
    const int bbase = blockIdx.x * 8 + wid * 4;
    const int b     = bbase + g;

    const float sL  = -LOG2E;
    const float s2L = -2.0f * LOG2E;
    const int ri = j, rf = 16 + j, rg = 32 + j, ro = 48 + j;

    // {wih*sc, bias*sc} pairs -> head as pk_mul with {x, 1.0}
    f32x2 wbi = { W_ih_f[ri] * sL,  (b_ih_f[ri] + b_hh_f[ri]) * sL  };
    f32x2 wbf = { W_ih_f[rf] * sL,  (b_ih_f[rf] + b_hh_f[rf]) * sL  };
    f32x2 wbg = { W_ih_f[rg] * s2L, (b_ih_f[rg] + b_hh_f[rg]) * s2L };
    f32x2 wbo = { W_ih_f[ro] * sL,  (b_ih_f[ro] + b_hh_f[ro]) * sL  };

    // rotation-permuted, prescaled W_hh slot pairs:
    // slot r (dpp row_ror:r) on lane j holds h_{(j-r)&15}
    f32x2 wi[8], wf[8], wg[8], wo[8];
#pragma unroll
    for (int r = 0; r < 8; ++r) {
        const int a0 = (j - 2 * r) & 15, a1 = (j - 2 * r - 1) & 15;
        wi[r] = (f32x2){ W_hh_f[ri * 16 + a0] * sL,  W_hh_f[ri * 16 + a1] * sL  };
        wf[r] = (f32x2){ W_hh_f[rf * 16 + a0] * sL,  W_hh_f[rf * 16 + a1] * sL  };
        wg[r] = (f32x2){ W_hh_f[rg * 16 + a0] * s2L, W_hh_f[rg * 16 + a1] * s2L };
        wo[r] = (f32x2){ W_hh_f[ro * 16 + a0] * sL,  W_hh_f[ro * 16 + a1] * sL  };
    }

    // stage x for the wave's 4 batches (coalesced 64-lane stores)
#pragma unroll
    for (int bb = 0; bb < 4; ++bb) {
        const int reg = (wid * 4 + bb) * 544;
#pragma unroll
        for (int i = 0; i < 8; ++i)
            smem[reg + i * 64 + lane] = x[(bbase + bb) * T_LEN + i * 64 + lane];
    }

    const int rbase = (wid * 4 + g) * 544;
    unsigned vX = (unsigned)(rbase * 4);     // byte addr of x[0] in this region
    const float k2 = s2L;
    float h_out;

// One step. v32={x,1.0(v33)}, acc pairs i/f/g/o = v[20:27], acts v28-31,
// c=v35, h=v36, slots v[48:63], x bufs v37/v38. Only DS op: next-x read.
#define STEP(XC, XN, XOFF) \
    "ds_read_b32 " XN ", %[vX] offset:" XOFF "\n\t" \
    "s_waitcnt lgkmcnt(1)\n\t" \
    "v_mov_b32 v32, " XC "\n\t" \
    "v_pk_mul_f32 v[20:21], v[32:33], %[wbi]\n\t" \
    "v_pk_mul_f32 v[22:23], v[32:33], %[wbf]\n\t" \
    "v_pk_mul_f32 v[24:25], v[32:33], %[wbg]\n\t" \
    "v_pk_mul_f32 v[26:27], v[32:33], %[wbo]\n\t" \
    "v_pk_fma_f32 v[20:21], v[48:49], %[wi0], v[20:21]\n\t" \
    "v_pk_fma_f32 v[22:23], v[48:49], %[wf0], v[22:23]\n\t" \
    "v_pk_fma_f32 v[24:25], v[48:49], %[wg0], v[24:25]\n\t" \
    "v_pk_fma_f32 v[26:27], v[48:49], %[wo0], v[26:27]\n\t" \
    "v_pk_fma_f32 v[20:21], v[50:51], %[wi1], v[20:21]\n\t" \
    "v_pk_fma_f32 v[22:23], v[50:51], %[wf1], v[22:23]\n\t" \
    "v_pk_fma_f32 v[24:25], v[50:51], %[wg1], v[24:25]\n\t" \
    "v_pk_fma_f32 v[26:27], v[50:51], %[wo1], v[26:27]\n\t" \
    "v_pk_fma_f32 v[20:21], v[52:53], %[wi2], v[20:21]\n\t" \
    "v_pk_fma_f32 v[22:23], v[52:53], %[wf2], v[22:23]\n\t" \
    "v_pk_fma_f32 v[24:25], v[52:53], %[wg2], v[24:25]\n\t" \
    "v_pk_fma_f32 v[26:27], v[52:53], %[wo2], v[26:27]\n\t" \
    "v_pk_fma_f32 v[20:21], v[54:55], %[wi3], v[20:21]\n\t" \
    "v_pk_fma_f32 v[22:23], v[54:55], %[wf3], v[22:23]\n\t" \
    "v_pk_fma_f32 v[24:25], v[54:55], %[wg3], v[24:25]\n\t" \
    "v_pk_fma_f32 v[26:27], v[54:55], %[wo3], v[26:27]\n\t" \
    "v_pk_fma_f32 v[20:21], v[56:57], %[wi4], v[20:21]\n\t" \
    "v_pk_fma_f32 v[22:23], v[56:57], %[wf4], v[22:23]\n\t" \
    "v_pk_fma_f32 v[24:25], v[56:57], %[wg4], v[24:25]\n\t" \
    "v_pk_fma_f32 v[26:27], v[56:57], %[wo4], v[26:27]\n\t" \
    "v_pk_fma_f32 v[20:21], v[58:59], %[wi5], v[20:21]\n\t" \
    "v_pk_fma_f32 v[22:23], v[58:59], %[wf5], v[22:23]\n\t" \
    "v_pk_fma_f32 v[24:25], v[58:59], %[wg5], v[24:25]\n\t" \
    "v_pk_fma_f32 v[26:27], v[58:59], %[wo5], v[26:27]\n\t" \
    "v_pk_fma_f32 v[20:21], v[60:61], %[wi6], v[20:21]\n\t" \
    "v_pk_fma_f32 v[22:23], v[60:61], %[wf6], v[22:23]\n\t" \
    "v_pk_fma_f32 v[24:25], v[60:61], %[wg6], v[24:25]\n\t" \
    "v_pk_fma_f32 v[26:27], v[60:61], %[wo6], v[26:27]\n\t" \
    "v_pk_fma_f32 v[20:21], v[62:63], %[wi7], v[20:21]\n\t" \
    "v_pk_fma_f32 v[22:23], v[62:63], %[wf7], v[22:23]\n\t" \
    "v_pk_fma_f32 v[24:25], v[62:63], %[wg7], v[24:25]\n\t" \
    "v_pk_fma_f32 v[26:27], v[62:63], %[wo7], v[26:27]\n\t" \
    "v_add_f32 v20, v20, v21\n\t" \
    "v_add_f32 v22, v22, v23\n\t" \
    "v_add_f32 v24, v24, v25\n\t" \
    "v_add_f32 v26, v26, v27\n\t" \
    "v_exp_f32 v28, v20\n\t" \
    "v_exp_f32 v29, v22\n\t" \
    "v_exp_f32 v30, v24\n\t" \
    "v_exp_f32 v31, v26\n\t" \
    "v_add_f32 v28, 1.0, v28\n\t" \
    "v_add_f32 v29, 1.0, v29\n\t" \
    "v_add_f32 v30, 1.0, v30\n\t" \
    "v_add_f32 v31, 1.0, v31\n\t" \
    "v_rcp_f32 v28, v28\n\t" \
    "v_rcp_f32 v29, v29\n\t" \
    "v_rcp_f32 v30, v30\n\t" \
    "v_rcp_f32 v31, v31\n\t" \
    "s_nop 0\n\t" \
    "v_fma_f32 v30, v30, 2.0, -1.0\n\t" \
    "v_mul_f32 v21, v28, v30\n\t" \
    "v_fma_f32 v35, v29, v35, v21\n\t" \
    "v_mul_f32 v34, %[k2], v35\n\t" \
    "v_exp_f32 v34, v34\n\t" \
    "s_nop 1\n\t" \
    "v_add_f32 v34, 1.0, v34\n\t" \
    "v_rcp_f32 v34, v34\n\t" \
    "s_nop 1\n\t" \
    "v_fma_f32 v34, v34, 2.0, -1.0\n\t" \
    "v_mul_f32 v36, v31, v34\n\t" \
    "s_nop 1\n\t" \
    "v_mov_b32 v48, v36\n\t" \
    "v_mov_b32_dpp v49, v36 row_ror:1 row_mask:0xf bank_mask:0xf\n\t" \
    "v_mov_b32_dpp v50, v36 row_ror:2 row_mask:0xf bank_mask:0xf\n\t" \
    "v_mov_b32_dpp v51, v36 row_ror:3 row_mask:0xf bank_mask:0xf\n\t" \
    "v_mov_b32_dpp v52, v36 row_ror:4 row_mask:0xf bank_mask:0xf\n\t" \
    "v_mov_b32_dpp v53, v36 row_ror:5 row_mask:0xf bank_mask:0xf\n\t" \
    "v_mov_b32_dpp v54, v36 row_ror:6 row_mask:0xf bank_mask:0xf\n\t" \
    "v_mov_b32_dpp v55, v36 row_ror:7 row_mask:0xf bank_mask:0xf\n\t" \
    "v_mov_b32_dpp v56, v36 row_ror:8 row_mask:0xf bank_mask:0xf\n\t" \
    "v_mov_b32_dpp v57, v36 row_ror:9 row_mask:0xf bank_mask:0xf\n\t" \
    "v_mov_b32_dpp v58, v36 row_ror:10 row_mask:0xf bank_mask:0xf\n\t" \
    "v_mov_b32_dpp v59, v36 row_ror:11 row_mask:0xf bank_mask:0xf\n\t" \
    "v_mov_b32_dpp v60, v36 row_ror:12 row_mask:0xf bank_mask:0xf\n\t" \
    "v_mov_b32_dpp v61, v36 row_ror:13 row_mask:0xf bank_mask:0xf\n\t" \
    "v_mov_b32_dpp v62, v36 row_ror:14 row_mask:0xf bank_mask:0xf\n\t" \
    "v_mov_b32_dpp v63, v36 row_ror:15 row_mask:0xf bank_mask:0xf\n\t"

    asm volatile(
        "s_waitcnt lgkmcnt(0)\n\t"           // staging writes drained
        "v_mov_b32 v33, 1.0\n\t"
        "v_mov_b32 v35, 0\n\t"               // c = 0
        "v_mov_b32 v48, 0\n\t" "v_mov_b32 v49, 0\n\t"
        "v_mov_b32 v50, 0\n\t" "v_mov_b32 v51, 0\n\t"
        "v_mov_b32 v52, 0\n\t" "v_mov_b32 v53, 0\n\t"
        "v_mov_b32 v54, 0\n\t" "v_mov_b32 v55, 0\n\t"
        "v_mov_b32 v56, 0\n\t" "v_mov_b32 v57, 0\n\t"
        "v_mov_b32 v58, 0\n\t" "v_mov_b32 v59, 0\n\t"
        "v_mov_b32 v60, 0\n\t" "v_mov_b32 v61, 0\n\t"
        "v_mov_b32 v62, 0\n\t" "v_mov_b32 v63, 0\n\t"
        "ds_read_b32 v37, %[vX] offset:0\n\t"   // x_0
        "s_mov_b32 s20, 0\n\t"
        "1:\n\t"
        STEP("v37", "v38", "4")
        STEP("v38", "v37", "8")
        STEP("v37", "v38", "12")
        STEP("v38", "v37", "16")
        STEP("v37", "v38", "20")
        STEP("v38", "v37", "24")
        STEP("v37", "v38", "28")
        STEP("v38", "v37", "32")
        "v_add_u32 %[vX], 32, %[vX]\n\t"
        "s_add_u32 s20, s20, 1\n\t"
        "s_cmp_lt_u32 s20, 64\n\t"
        "s_cbranch_scc1 1b\n\t"
        "v_mov_b32 %[ho], v36\n\t"
        "s_waitcnt lgkmcnt(0)\n\t"
        : [vX]"+v"(vX), [ho]"=v"(h_out)
        : [k2]"s"(k2),
          [wbi]"v"(wbi), [wbf]"v"(wbf), [wbg]"v"(wbg), [wbo]"v"(wbo),
          [wi0]"v"(wi[0]), [wi1]"v"(wi[1]), [wi2]"v"(wi[2]), [wi3]"v"(wi[3]),
          [wi4]"v"(wi[4]), [wi5]"v"(wi[5]), [wi6]"v"(wi[6]), [wi7]"v"(wi[7]),
          [wf0]"v"(wf[0]), [wf1]"v"(wf[1]), [wf2]"v"(wf[2]), [wf3]"v"(wf[3]),
          [wf4]"v"(wf[4]), [wf5]"v"(wf[5]), [wf6]"v"(wf[6]), [wf7]"v"(wf[7]),
          [wg0]"v"(wg[0]), [wg1]"v"(wg[1]), [wg2]"v"(wg[2]), [wg3]"v"(wg[3]),
          [wg4]"v"(wg[4]), [wg5]"v"(wg[5]), [wg6]"v"(wg[6]), [wg7]"v"(wg[7]),
          [wo0]"v"(wo[0]), [wo1]"v"(wo[1]), [wo2]"v"(wo[2]), [wo3]"v"(wo[3]),
          [wo4]"v"(wo[4]), [wo5]"v"(wo[5]), [wo6]"v"(wo[6]), [wo7]"v"(wo[7])
        : "v20","v21","v22","v23","v24","v25","v26","v27","v28","v29",
          "v30","v31","v32","v33","v34","v35","v36","v37","v38",
          "v48","v49","v50","v51","v52","v53","v54","v55",
          "v56","v57","v58","v59","v60","v61","v62","v63",
          "s20","scc","memory");
#undef STEP

    // publish forward hidden state
    smem[rbase + 512 + j] = h_out;

    // ---- reverse direction: one LSTM step on x[:, T-1] from zero state ----
    const float xl = smem[rbase + 511];
    const float zi = fmaf(xl, W_ih_r[j],      b_ih_r[j]      + b_hh_r[j]);
    const float zg = fmaf(xl, W_ih_r[32 + j], b_ih_r[32 + j] + b_hh_r[32 + j]);
    const float zo = fmaf(xl, W_ih_r[48 + j], b_ih_r[48 + j] + b_hh_r[48 + j]);
    const float si = __builtin_amdgcn_rcpf(1.0f + __builtin_amdgcn_exp2f(zi * sL));
    const float tg = fmaf(__builtin_amdgcn_rcpf(1.0f + __builtin_amdgcn_exp2f(zg * s2L)), 2.0f, -1.0f);
    const float so = __builtin_amdgcn_rcpf(1.0f + __builtin_amdgcn_exp2f(zo * sL));
    const float cr = si * tg;
    const float th = fmaf(__builtin_amdgcn_rcpf(1.0f + __builtin_amdgcn_exp2f(cr * s2L)), 2.0f, -1.0f);
    smem[rbase + 528 + j] = so * th;
    __syncthreads();

    // ---- MLP head: lane j computes hid[j] for its group's batch ----
    float hid = b1[j];
#pragma unroll
    for (int n = 0; n < 16; ++n) hid = fmaf(smem[rbase + 512 + n], W1[j * 32 + n],      hid);
#pragma unroll
    for (int n = 0; n < 16; ++n) hid = fmaf(smem[rbase + 528 + n], W1[j * 32 + 16 + n], hid);
    hid = (hid > 0.0f) ? hid : (0.2f * hid);

    float v = hid * W2[j];
    v += __shfl_xor(v, 1);
    v += __shfl_xor(v, 2);
    v += __shfl_xor(v, 4);
    v += __shfl_xor(v, 8);
    if (j == 0) out[b] = v + b2[0];
}

extern "C" void kernel_launch(void* const* d_in, const int* in_sizes, int n_in,
                              void* d_out, int out_size, void* d_ws, size_t ws_size,
                              hipStream_t stream) {
    const float* x      = (const float*)d_in[0];
    const float* W_ih_f = (const float*)d_in[1];
    const float* W_hh_f = (const float*)d_in[2];
    const float* b_ih_f = (const float*)d_in[3];
    const float* b_hh_f = (const float*)d_in[4];
    const float* W_ih_r = (const float*)d_in[5];
    const float* W_hh_r = (const float*)d_in[6];
    const float* b_ih_r = (const float*)d_in[7];
    const float* b_hh_r = (const float*)d_in[8];
    const float* W1     = (const float*)d_in[9];
    const float* b1     = (const float*)d_in[10];
    const float* W2     = (const float*)d_in[11];
    const float* b2     = (const float*)d_in[12];
    float* out = (float*)d_out;

    const int B = in_sizes[0] / T_LEN;   // 2048
    dim3 grid(B / 8), block(128);        // 2 waves/block, 4 batches/wave
    size_t lds_bytes = 8 * 544 * sizeof(float);   // 17408 B/block
    hipLaunchKernelGGL(bilstm_head_kernel, grid, block, lds_bytes, stream,
                       x, W_ih_f, W_hh_f, b_ih_f, b_hh_f,
                       W_ih_r, W_hh_r, b_ih_r, b_hh_r,
                       W1, b1, W2, b2, out);
}

// Round 13
// 90.179 us; speedup vs baseline: 1.1053x; 1.1053x over previous
//
#include <hip/hip_runtime.h>

#define T_LEN 512
#define LOG2E 1.4426950408889634f

typedef float f32x2 __attribute__((ext_vector_type(2)));

// v12 "layout F": 2 batches/wave, 32 lanes/batch, zero-LDS h broadcast.
//   row = lane>>4 (0..3), j = lane&15.
//   rows 0,2 = batch A; rows 1,3 = batch B  (same batch 32 lanes apart!)
//   rows 0/1: lane owns gate rows {i_j (chain a), f_j (chain b)}  (sigma,sigma)
//   rows 2/3: lane owns gate rows {g_j (chain a), o_j (chain b)}  (tanh,sigma)
// Per step: 16 pk_fma matvec (4 split chains), acts, then:
//   2x v_permlane32_swap pull {tanh_g, sig_o} from lane+32 down to rows 0/1,
//   c,h computed on lanes 0-31, 1x swap replicates h up to rows 2/3,
//   15x v_mov_b32_dpp row_ror build rotated slots (weights pre-permuted, v11-
//   validated). Only DS op in loop: one x read (double-buffered).
// permlane32_swap half-orientation is runtime-detected in the asm preamble;
// two loop bodies (operand-swapped) make correctness orientation-proof.
// LDS region per batch: [x 512][hf 16][hb 16] = 544 floats.
__global__ __launch_bounds__(256, 1) void bilstm_head_kernel(
    const float* __restrict__ x,
    const float* __restrict__ W_ih_f, const float* __restrict__ W_hh_f,
    const float* __restrict__ b_ih_f, const float* __restrict__ b_hh_f,
    const float* __restrict__ W_ih_r, const float* __restrict__ W_hh_r,
    const float* __restrict__ b_ih_r, const float* __restrict__ b_hh_r,
    const float* __restrict__ W1, const float* __restrict__ b1,
    const float* __restrict__ W2, const float* __restrict__ b2,
    float* __restrict__ out)
{
    extern __shared__ float smem[];          // 8 regions * 544 floats

    const int tid  = threadIdx.x;
    const int wid  = tid >> 6;
    const int lane = tid & 63;
    const int row  = lane >> 4;              // 0..3
    const int j    = lane & 15;              // hidden index
    const int hi2  = row >> 1;               // 0: i/f rows, 1: g/o rows
    const int myb  = row & 1;                // 0: batch A, 1: batch B
    const int bA   = blockIdx.x * 8 + wid * 2;
    const int bB   = bA + 1;

    const float sL  = -LOG2E;
    const float s2L = -2.0f * LOG2E;
    const int   raw = hi2 ? (32 + j) : j;         // chain a gate row
    const int   rbw = hi2 ? (48 + j) : (16 + j);  // chain b gate row
    const float sa  = hi2 ? s2L : sL;
    const float sb  = sL;
    const float cma = hi2 ? 2.0f : 1.0f;          // tanh fix only on g rows
    const float caa = hi2 ? -1.0f : 0.0f;
    const float k2  = s2L;

    const float wha = W_ih_f[raw] * sa;
    const float bba = (b_ih_f[raw] + b_hh_f[raw]) * sa;
    const float whb = W_ih_f[rbw] * sb;
    const float bbb = (b_ih_f[rbw] + b_hh_f[rbw]) * sb;

    // rotation-permuted prescaled W_hh slot pairs (v11-validated formula):
    // slot r (row_ror:r) on lane j holds h_{(j-r)&15}
    f32x2 wa[8], wb[8];
#pragma unroll
    for (int r = 0; r < 8; ++r) {
        const int a0 = (j - 2 * r) & 15, a1 = (j - 2 * r - 1) & 15;
        wa[r] = (f32x2){ W_hh_f[raw * 16 + a0] * sa, W_hh_f[raw * 16 + a1] * sa };
        wb[r] = (f32x2){ W_hh_f[rbw * 16 + a0] * sb, W_hh_f[rbw * 16 + a1] * sb };
    }

    const int rA = (wid * 2) * 544, rB = rA + 544;
    // stage both batches' x rows (coalesced 64-lane stores)
#pragma unroll
    for (int i = 0; i < 8; ++i) {
        smem[rA + i * 64 + lane] = x[bA * T_LEN + i * 64 + lane];
        smem[rB + i * 64 + lane] = x[bB * T_LEN + i * 64 + lane];
    }

    const int myr = myb ? rB : rA;
    unsigned vX = (unsigned)(myr * 4);       // byte addr of x[0] in my region
    float h_out;
    const int lid = lane;

// one LSTM step; S1/S2 pull acts hi->lo, S3 replicates h lo->hi.
#define STEP(XC, XN, XOFF, S1, S2, S3) \
    "ds_read_b32 " XN ", %[vX] offset:" XOFF "\n\t" \
    "s_waitcnt lgkmcnt(1)\n\t" \
    "v_fma_f32 v20, " XC ", %[wha], %[bba]\n\t" \
    "v_mov_b32 v21, 0\n\t" \
    "v_fma_f32 v22, " XC ", %[whb], %[bbb]\n\t" \
    "v_mov_b32 v23, 0\n\t" \
    "v_pk_mul_f32 v[16:17], v[56:57], %[wa4]\n\t" \
    "v_pk_mul_f32 v[18:19], v[56:57], %[wb4]\n\t" \
    "v_pk_fma_f32 v[20:21], v[48:49], %[wa0], v[20:21]\n\t" \
    "v_pk_fma_f32 v[22:23], v[48:49], %[wb0], v[22:23]\n\t" \
    "v_pk_fma_f32 v[16:17], v[58:59], %[wa5], v[16:17]\n\t" \
    "v_pk_fma_f32 v[18:19], v[58:59], %[wb5], v[18:19]\n\t" \
    "v_pk_fma_f32 v[20:21], v[50:51], %[wa1], v[20:21]\n\t" \
    "v_pk_fma_f32 v[22:23], v[50:51], %[wb1], v[22:23]\n\t" \
    "v_pk_fma_f32 v[16:17], v[60:61], %[wa6], v[16:17]\n\t" \
    "v_pk_fma_f32 v[18:19], v[60:61], %[wb6], v[18:19]\n\t" \
    "v_pk_fma_f32 v[20:21], v[52:53], %[wa2], v[20:21]\n\t" \
    "v_pk_fma_f32 v[22:23], v[52:53], %[wb2], v[22:23]\n\t" \
    "v_pk_fma_f32 v[16:17], v[62:63], %[wa7], v[16:17]\n\t" \
    "v_pk_fma_f32 v[18:19], v[62:63], %[wb7], v[18:19]\n\t" \
    "v_pk_fma_f32 v[20:21], v[54:55], %[wa3], v[20:21]\n\t" \
    "v_pk_fma_f32 v[22:23], v[54:55], %[wb3], v[22:23]\n\t" \
    "v_pk_add_f32 v[20:21], v[20:21], v[16:17]\n\t" \
    "v_pk_add_f32 v[22:23], v[22:23], v[18:19]\n\t" \
    "v_add_f32 v20, v20, v21\n\t" \
    "v_add_f32 v22, v22, v23\n\t" \
    "v_exp_f32 v24, v20\n\t" \
    "v_exp_f32 v25, v22\n\t" \
    "s_nop 1\n\t" \
    "v_add_f32 v24, 1.0, v24\n\t" \
    "v_add_f32 v25, 1.0, v25\n\t" \
    "v_rcp_f32 v24, v24\n\t" \
    "v_rcp_f32 v25, v25\n\t" \
    "s_nop 1\n\t" \
    "v_fma_f32 v26, v24, %[cma], %[caa]\n\t" \
    "s_nop 1\n\t" \
    S1 \
    S2 \
    "s_nop 1\n\t" \
    "v_mul_f32 v34, v26, v28\n\t" \
    "v_fma_f32 v35, v25, v35, v34\n\t" \
    "v_mul_f32 v34, %[k2], v35\n\t" \
    "v_exp_f32 v34, v34\n\t" \
    "s_nop 1\n\t" \
    "v_add_f32 v34, 1.0, v34\n\t" \
    "v_rcp_f32 v34, v34\n\t" \
    "s_nop 1\n\t" \
    "v_fma_f32 v34, v34, 2.0, -1.0\n\t" \
    "v_mul_f32 v36, v29, v34\n\t" \
    "s_nop 1\n\t" \
    "v_mov_b32 v33, v36\n\t" \
    "s_nop 1\n\t" \
    S3 \
    "s_nop 1\n\t" \
    "v_mov_b32 v48, v36\n\t" \
    "v_mov_b32_dpp v49, v36 row_ror:1 row_mask:0xf bank_mask:0xf\n\t" \
    "v_mov_b32_dpp v50, v36 row_ror:2 row_mask:0xf bank_mask:0xf\n\t" \
    "v_mov_b32_dpp v51, v36 row_ror:3 row_mask:0xf bank_mask:0xf\n\t" \
    "v_mov_b32_dpp v52, v36 row_ror:4 row_mask:0xf bank_mask:0xf\n\t" \
    "v_mov_b32_dpp v53, v36 row_ror:5 row_mask:0xf bank_mask:0xf\n\t" \
    "v_mov_b32_dpp v54, v36 row_ror:6 row_mask:0xf bank_mask:0xf\n\t" \
    "v_mov_b32_dpp v55, v36 row_ror:7 row_mask:0xf bank_mask:0xf\n\t" \
    "v_mov_b32_dpp v56, v36 row_ror:8 row_mask:0xf bank_mask:0xf\n\t" \
    "v_mov_b32_dpp v57, v36 row_ror:9 row_mask:0xf bank_mask:0xf\n\t" \
    "v_mov_b32_dpp v58, v36 row_ror:10 row_mask:0xf bank_mask:0xf\n\t" \
    "v_mov_b32_dpp v59, v36 row_ror:11 row_mask:0xf bank_mask:0xf\n\t" \
    "v_mov_b32_dpp v60, v36 row_ror:12 row_mask:0xf bank_mask:0xf\n\t" \
    "v_mov_b32_dpp v61, v36 row_ror:13 row_mask:0xf bank_mask:0xf\n\t" \
    "v_mov_b32_dpp v62, v36 row_ror:14 row_mask:0xf bank_mask:0xf\n\t" \
    "v_mov_b32_dpp v63, v36 row_ror:15 row_mask:0xf bank_mask:0xf\n\t"

// orientation X: vD.lo <- vS.hi ; vS.hi <- vD.lo
#define S1X "v_permlane32_swap_b32 v28, v26\n\t"
#define S2X "v_permlane32_swap_b32 v29, v25\n\t"
#define S3X "v_permlane32_swap_b32 v33, v36\n\t"
// orientation Y (mirrored): vD.hi <- vS.lo ; vS.lo <- vD.hi
#define S1Y "v_permlane32_swap_b32 v26, v28\n\t"
#define S2Y "v_permlane32_swap_b32 v25, v29\n\t"
#define S3Y "v_permlane32_swap_b32 v36, v33\n\t"

    asm volatile(
        "s_waitcnt lgkmcnt(0)\n\t"           // x staging drained
        "v_mov_b32 v35, 0\n\t"               // c = 0
        "v_mov_b32 v48, 0\n\t" "v_mov_b32 v49, 0\n\t"
        "v_mov_b32 v50, 0\n\t" "v_mov_b32 v51, 0\n\t"
        "v_mov_b32 v52, 0\n\t" "v_mov_b32 v53, 0\n\t"
        "v_mov_b32 v54, 0\n\t" "v_mov_b32 v55, 0\n\t"
        "v_mov_b32 v56, 0\n\t" "v_mov_b32 v57, 0\n\t"
        "v_mov_b32 v58, 0\n\t" "v_mov_b32 v59, 0\n\t"
        "v_mov_b32 v60, 0\n\t" "v_mov_b32 v61, 0\n\t"
        "v_mov_b32 v62, 0\n\t" "v_mov_b32 v63, 0\n\t"
        "ds_read_b32 v30, %[vX] offset:0\n\t"   // x_0
        // ---- runtime orientation probe: marker swap + readfirstlane ----
        "v_mov_b32 v33, %[lid]\n\t"
        "v_add_u32 v34, 64, v33\n\t"
        "s_nop 1\n\t"
        "v_permlane32_swap_b32 v34, v33\n\t"
        "s_nop 1\n\t"
        "v_readfirstlane_b32 s21, v34\n\t"
        "s_nop 4\n\t"
        "s_mov_b32 s20, 0\n\t"
        "s_cmp_eq_u32 s21, 32\n\t"           // lane0 sees 32 -> orientation X
        "s_cbranch_scc1 3f\n\t"
        // ================= Y path =================
        "1:\n\t"
        STEP("v30", "v31", "4",  S1Y, S2Y, S3Y)
        STEP("v31", "v30", "8",  S1Y, S2Y, S3Y)
        STEP("v30", "v31", "12", S1Y, S2Y, S3Y)
        STEP("v31", "v30", "16", S1Y, S2Y, S3Y)
        STEP("v30", "v31", "20", S1Y, S2Y, S3Y)
        STEP("v31", "v30", "24", S1Y, S2Y, S3Y)
        STEP("v30", "v31", "28", S1Y, S2Y, S3Y)
        STEP("v31", "v30", "32", S1Y, S2Y, S3Y)
        "v_add_u32 %[vX], 32, %[vX]\n\t"
        "s_add_u32 s20, s20, 1\n\t"
        "s_cmp_lt_u32 s20, 64\n\t"
        "s_cbranch_scc1 1b\n\t"
        "s_branch 4f\n\t"
        // ================= X path =================
        "3:\n\t"
        "2:\n\t"
        STEP("v30", "v31", "4",  S1X, S2X, S3X)
        STEP("v31", "v30", "8",  S1X, S2X, S3X)
        STEP("v30", "v31", "12", S1X, S2X, S3X)
        STEP("v31", "v30", "16", S1X, S2X, S3X)
        STEP("v30", "v31", "20", S1X, S2X, S3X)
        STEP("v31", "v30", "24", S1X, S2X, S3X)
        STEP("v30", "v31", "28", S1X, S2X, S3X)
        STEP("v31", "v30", "32", S1X, S2X, S3X)
        "v_add_u32 %[vX], 32, %[vX]\n\t"
        "s_add_u32 s20, s20, 1\n\t"
        "s_cmp_lt_u32 s20, 64\n\t"
        "s_cbranch_scc1 2b\n\t"
        "4:\n\t"
        "v_mov_b32 %[ho], v36\n\t"
        "s_waitcnt lgkmcnt(0)\n\t"
        : [vX]"+v"(vX), [ho]"=v"(h_out)
        : [lid]"v"(lid), [k2]"s"(k2),
          [wha]"v"(wha), [bba]"v"(bba), [whb]"v"(whb), [bbb]"v"(bbb),
          [cma]"v"(cma), [caa]"v"(caa),
          [wa0]"v"(wa[0]), [wa1]"v"(wa[1]), [wa2]"v"(wa[2]), [wa3]"v"(wa[3]),
          [wa4]"v"(wa[4]), [wa5]"v"(wa[5]), [wa6]"v"(wa[6]), [wa7]"v"(wa[7]),
          [wb0]"v"(wb[0]), [wb1]"v"(wb[1]), [wb2]"v"(wb[2]), [wb3]"v"(wb[3]),
          [wb4]"v"(wb[4]), [wb5]"v"(wb[5]), [wb6]"v"(wb[6]), [wb7]"v"(wb[7])
        : "v16","v17","v18","v19","v20","v21","v22","v23","v24","v25",
          "v26","v27","v28","v29","v30","v31","v32","v33","v34","v35","v36",
          "v48","v49","v50","v51","v52","v53","v54","v55",
          "v56","v57","v58","v59","v60","v61","v62","v63",
          "s20","s21","scc","memory");
#undef STEP
#undef S1X
#undef S2X
#undef S3X
#undef S1Y
#undef S2Y
#undef S3Y

    // h valid (replicated) on all lanes; lanes 0-15 = A's h_j, 16-31 = B's h_j
    if (lane < 32) {
        const int reg = (lane >> 4) ? rB : rA;
        smem[reg + 512 + j] = h_out;

        // reverse direction: one LSTM step on x[:, T-1] from zero state
        const float xl = smem[reg + 511];
        const float zi = fmaf(xl, W_ih_r[j],      b_ih_r[j]      + b_hh_r[j]);
        const float zg = fmaf(xl, W_ih_r[32 + j], b_ih_r[32 + j] + b_hh_r[32 + j]);
        const float zo = fmaf(xl, W_ih_r[48 + j], b_ih_r[48 + j] + b_hh_r[48 + j]);
        const float si = __builtin_amdgcn_rcpf(1.0f + __builtin_amdgcn_exp2f(zi * sL));
        const float tg = fmaf(__builtin_amdgcn_rcpf(1.0f + __builtin_amdgcn_exp2f(zg * s2L)), 2.0f, -1.0f);
        const float so = __builtin_amdgcn_rcpf(1.0f + __builtin_amdgcn_exp2f(zo * sL));
        const float cr = si * tg;
        const float th = fmaf(__builtin_amdgcn_rcpf(1.0f + __builtin_amdgcn_exp2f(cr * s2L)), 2.0f, -1.0f);
        smem[reg + 528 + j] = so * th;
    }
    __syncthreads();

    // ---- MLP head: lanes 0-15 -> batch A, 16-31 -> batch B ----
    if (lane < 32) {
        const int reg = (lane >> 4) ? rB : rA;
        const int bo  = (lane >> 4) ? bB : bA;
        float hid = b1[j];
#pragma unroll
        for (int n = 0; n < 16; ++n) hid = fmaf(smem[reg + 512 + n], W1[j * 32 + n],      hid);
#pragma unroll
        for (int n = 0; n < 16; ++n) hid = fmaf(smem[reg + 528 + n], W1[j * 32 + 16 + n], hid);
        hid = (hid > 0.0f) ? hid : (0.2f * hid);

        float v = hid * W2[j];
        v += __shfl_xor(v, 1);
        v += __shfl_xor(v, 2);
        v += __shfl_xor(v, 4);
        v += __shfl_xor(v, 8);
        if (j == 0) out[bo] = v + b2[0];
    }
}

extern "C" void kernel_launch(void* const* d_in, const int* in_sizes, int n_in,
                              void* d_out, int out_size, void* d_ws, size_t ws_size,
                              hipStream_t stream) {
    const float* x      = (const float*)d_in[0];
    const float* W_ih_f = (const float*)d_in[1];
    const float* W_hh_f = (const float*)d_in[2];
    const float* b_ih_f = (const float*)d_in[3];
    const float* b_hh_f = (const float*)d_in[4];
    const float* W_ih_r = (const float*)d_in[5];
    const float* W_hh_r = (const float*)d_in[6];
    const float* b_ih_r = (const float*)d_in[7];
    const float* b_hh_r = (const float*)d_in[8];
    const float* W1     = (const float*)d_in[9];
    const float* b1     = (const float*)d_in[10];
    const float* W2     = (const float*)d_in[11];
    const float* b2     = (const float*)d_in[12];
    float* out = (float*)d_out;

    const int B = in_sizes[0] / T_LEN;   // 2048
    dim3 grid(B / 8), block(256);        // 4 waves/block, 2 batches/wave
    size_t lds_bytes = 8 * 544 * sizeof(float);   // 17408 B/block
    hipLaunchKernelGGL(bilstm_head_kernel, grid, block, lds_bytes, stream,
                       x, W_ih_f, W_hh_f, b_ih_f, b_hh_f,
                       W_ih_r, W_hh_r, b_ih_r, b_hh_r,
                       W1, b1, W2, b2, out);
}

// Round 14
// 69.917 us; speedup vs baseline: 1.4256x; 1.2898x over previous
//
#include <hip/hip_runtime.h>

#define T_LEN 512
#define LOG2E 1.4426950408889634f

typedef float f32x2 __attribute__((ext_vector_type(2)));

// v13 = R7 (proven 78.0 steady) with the per-step x-read machinery removed:
// 2 batches/wave (lanes 0-31 batch A, 32-63 batch B); hl=lane&31, k=hl>>1,
// p=hl&1; sub-row0 = {i,f}[k] (sigmoid), sub-row1 = {g,o}[k] (tanh/sigmoid).
// x[t..t+7] held in v[8:15] via 2 uniform ds_read_b128 per 8-step iteration
// (refilled in steps 3/7 trans shadows) -> step head z-fma needs NO wait and
// fills the first lgkm shadow. h broadcast unchanged: p0 lanes ds_write h[k],
// all lanes 4x uniform ds_read_b128; in-order queue [w,r1..r4(+refill)] ->
// staggered waits (3)(2)(1)(0). v_mul hoisted into DPP hazard slots.
// LDS per batch: [h 16][hbwd 16][x 512][pad 16] = 560 floats.
__global__ __launch_bounds__(256, 1) void bilstm_head_kernel(
    const float* __restrict__ x,
    const float* __restrict__ W_ih_f, const float* __restrict__ W_hh_f,
    const float* __restrict__ b_ih_f, const float* __restrict__ b_hh_f,
    const float* __restrict__ W_ih_r, const float* __restrict__ W_hh_r,
    const float* __restrict__ b_ih_r, const float* __restrict__ b_hh_r,
    const float* __restrict__ W1, const float* __restrict__ b1,
    const float* __restrict__ W2, const float* __restrict__ b2,
    float* __restrict__ out)
{
    extern __shared__ float smem[];          // 8 regions * 560 floats

    const int tid  = threadIdx.x;
    const int wid  = tid >> 6;
    const int lane = tid & 63;
    const int half = lane >> 5;
    const int hl   = lane & 31;
    const int b    = blockIdx.x * 8 + wid * 2 + half;

    const int k = hl >> 1;
    const int p = hl & 1;
    const int row0 = p * 16 + k;             // sigmoid row (i or f)
    const int row1 = (2 + p) * 16 + k;       // g (tanh) or o (sigmoid)

    const float c1_0 = -LOG2E;
    const float c1_1 = (p == 0) ? (-2.0f * LOG2E) : (-LOG2E);
    const float cm1  = (p == 0) ? 2.0f : 1.0f;
    const float ca1  = (p == 0) ? -1.0f : 0.0f;
    const float k2   = -2.0f * LOG2E;

    // prescaled weights: matvec result feeds v_exp directly
    const float wih0  = W_ih_f[row0] * c1_0;
    const float bias0 = (b_ih_f[row0] + b_hh_f[row0]) * c1_0;
    const float wih1  = W_ih_f[row1] * c1_1;
    const float bias1 = (b_ih_f[row1] + b_hh_f[row1]) * c1_1;
    f32x2 w0p[8], w1p[8];
#pragma unroll
    for (int n = 0; n < 8; ++n) {
        w0p[n].x = W_hh_f[row0 * 16 + 2 * n]     * c1_0;
        w0p[n].y = W_hh_f[row0 * 16 + 2 * n + 1] * c1_0;
        w1p[n].x = W_hh_f[row1 * 16 + 2 * n]     * c1_1;
        w1p[n].y = W_hh_f[row1 * 16 + 2 * n + 1] * c1_1;
    }

    const int rbase = (wid * 2 + half) * 560;        // region base (floats)
    // stage this batch's x row (32 lanes per batch)
#pragma unroll
    for (int i = 0; i < 16; ++i)
        smem[rbase + 32 + i * 32 + hl] = x[b * T_LEN + i * 32 + hl];

    const unsigned vB = (unsigned)(rbase * 4);               // h read base
    const unsigned vW = (unsigned)((rbase + p * 16 + k) * 4); // h write addr
    unsigned vX = (unsigned)((rbase + 32) * 4);              // x byte base
    float c = 0.0f;

// One LSTM step. XC = x register (v8..v15). FILL = trans-shadow filler
// (s_nop 0, or the x refill ds_read in steps 3/7).
#define LSTM_STEP(XC, FILL) \
    "v_fma_f32 v20, " XC ", %[wih0], %[bias0]\n\t" \
    "v_mov_b32 v21, 0\n\t" \
    "v_fma_f32 v22, " XC ", %[wih1], %[bias1]\n\t" \
    "v_mov_b32 v23, 0\n\t" \
    "s_waitcnt lgkmcnt(3)\n\t" \
    "v_pk_fma_f32 v[20:21], v[32:33], %[w00], v[20:21]\n\t" \
    "v_pk_fma_f32 v[22:23], v[32:33], %[w10], v[22:23]\n\t" \
    "v_pk_fma_f32 v[20:21], v[34:35], %[w01], v[20:21]\n\t" \
    "v_pk_fma_f32 v[22:23], v[34:35], %[w11], v[22:23]\n\t" \
    "s_waitcnt lgkmcnt(2)\n\t" \
    "v_pk_fma_f32 v[20:21], v[36:37], %[w02], v[20:21]\n\t" \
    "v_pk_fma_f32 v[22:23], v[36:37], %[w12], v[22:23]\n\t" \
    "v_pk_fma_f32 v[20:21], v[38:39], %[w03], v[20:21]\n\t" \
    "v_pk_fma_f32 v[22:23], v[38:39], %[w13], v[22:23]\n\t" \
    "s_waitcnt lgkmcnt(1)\n\t" \
    "v_pk_fma_f32 v[20:21], v[40:41], %[w04], v[20:21]\n\t" \
    "v_pk_fma_f32 v[22:23], v[40:41], %[w14], v[22:23]\n\t" \
    "v_pk_fma_f32 v[20:21], v[42:43], %[w05], v[20:21]\n\t" \
    "v_pk_fma_f32 v[22:23], v[42:43], %[w15], v[22:23]\n\t" \
    "s_waitcnt lgkmcnt(0)\n\t" \
    "v_pk_fma_f32 v[20:21], v[44:45], %[w06], v[20:21]\n\t" \
    "v_pk_fma_f32 v[22:23], v[44:45], %[w16], v[22:23]\n\t" \
    "v_pk_fma_f32 v[20:21], v[46:47], %[w07], v[20:21]\n\t" \
    "v_pk_fma_f32 v[22:23], v[46:47], %[w17], v[22:23]\n\t" \
    "v_add_f32 v20, v20, v21\n\t" \
    "v_add_f32 v22, v22, v23\n\t" \
    "v_exp_f32 v24, v20\n\t" \
    "v_exp_f32 v25, v22\n\t" \
    FILL \
    "v_add_f32 v24, 1.0, v24\n\t" \
    "v_add_f32 v25, 1.0, v25\n\t" \
    "v_rcp_f32 v24, v24\n\t" \
    "v_rcp_f32 v25, v25\n\t" \
    "s_nop 1\n\t" \
    "v_fma_f32 v25, v25, %[cm1], %[ca1]\n\t" \
    "v_mul_f32 v28, v24, v25\n\t" \
    "v_mov_b32_dpp v26, v24 quad_perm:[1,0,3,2] row_mask:0xf bank_mask:0xf\n\t" \
    "v_mov_b32_dpp v27, v25 quad_perm:[1,0,3,2] row_mask:0xf bank_mask:0xf\n\t" \
    "v_fma_f32 %[c], v26, %[c], v28\n\t" \
    "v_mul_f32 v28, %[k2], %[c]\n\t" \
    "v_exp_f32 v28, v28\n\t" \
    "s_nop 1\n\t" \
    "v_add_f32 v28, 1.0, v28\n\t" \
    "v_rcp_f32 v28, v28\n\t" \
    "s_nop 1\n\t" \
    "v_fma_f32 v28, v28, 2.0, -1.0\n\t" \
    "v_mul_f32 v29, v27, v28\n\t" \
    "ds_write_b32 %[vW], v29\n\t" \
    "ds_read_b128 v[32:35], %[vB] offset:0\n\t" \
    "ds_read_b128 v[36:39], %[vB] offset:16\n\t" \
    "ds_read_b128 v[40:43], %[vB] offset:32\n\t" \
    "ds_read_b128 v[44:47], %[vB] offset:48\n\t"

#define NOFILL "s_nop 0\n\t"
#define FILLA  "ds_read_b128 v[8:11], %[vX] offset:32\n\t"
#define FILLB  "ds_read_b128 v[12:15], %[vX] offset:48\n\t"

    asm volatile(
        "s_waitcnt lgkmcnt(0)\n\t"           // x staging drained
        "v_mov_b32 v29, 0\n\t"
        "ds_read_b128 v[8:11],  %[vX] offset:0\n\t"   // x0..x3
        "ds_read_b128 v[12:15], %[vX] offset:16\n\t"  // x4..x7
        "ds_write_b32 %[vW], v29\n\t"                 // h=0 publish
        "ds_read_b128 v[32:35], %[vB] offset:0\n\t"
        "ds_read_b128 v[36:39], %[vB] offset:16\n\t"
        "ds_read_b128 v[40:43], %[vB] offset:32\n\t"
        "ds_read_b128 v[44:47], %[vB] offset:48\n\t"
        "s_waitcnt lgkmcnt(4)\n\t"           // xA,xB,write retired
        "s_mov_b32 s20, 0\n\t"
        "1:\n\t"
        LSTM_STEP("v8",  NOFILL)
        LSTM_STEP("v9",  NOFILL)
        LSTM_STEP("v10", NOFILL)
        LSTM_STEP("v11", FILLA)
        LSTM_STEP("v12", NOFILL)
        LSTM_STEP("v13", NOFILL)
        LSTM_STEP("v14", NOFILL)
        LSTM_STEP("v15", FILLB)
        "v_add_u32 %[vX], 32, %[vX]\n\t"
        "s_add_u32 s20, s20, 1\n\t"
        "s_cmp_lt_u32 s20, 64\n\t"
        "s_cbranch_scc1 1b\n\t"
        "s_waitcnt lgkmcnt(0)\n\t"           // final h write drained
        : [c]"+v"(c), [vX]"+v"(vX)
        : [vB]"v"(vB), [vW]"v"(vW),
          [wih0]"v"(wih0), [bias0]"v"(bias0),
          [wih1]"v"(wih1), [bias1]"v"(bias1),
          [cm1]"v"(cm1), [ca1]"v"(ca1), [k2]"v"(k2),
          [w00]"v"(w0p[0]), [w01]"v"(w0p[1]), [w02]"v"(w0p[2]), [w03]"v"(w0p[3]),
          [w04]"v"(w0p[4]), [w05]"v"(w0p[5]), [w06]"v"(w0p[6]), [w07]"v"(w0p[7]),
          [w10]"v"(w1p[0]), [w11]"v"(w1p[1]), [w12]"v"(w1p[2]), [w13]"v"(w1p[3]),
          [w14]"v"(w1p[4]), [w15]"v"(w1p[5]), [w16]"v"(w1p[6]), [w17]"v"(w1p[7])
        : "v8","v9","v10","v11","v12","v13","v14","v15",
          "v20","v21","v22","v23","v24","v25","v26","v27","v28","v29",
          "v32","v33","v34","v35","v36","v37","v38","v39",
          "v40","v41","v42","v43","v44","v45","v46","v47",
          "s20","scc","memory");
#undef LSTM_STEP
#undef NOFILL
#undef FILLA
#undef FILLB

    // ---- reverse direction: one step on x[:, T-1], zero state; lanes hl<16
    if (hl < 16) {
        const int j = hl;
        const float xl = smem[rbase + 32 + 511];
        const float zi = fmaf(xl, W_ih_r[j],      b_ih_r[j]      + b_hh_r[j]);
        const float zg = fmaf(xl, W_ih_r[32 + j], b_ih_r[32 + j] + b_hh_r[32 + j]);
        const float zo = fmaf(xl, W_ih_r[48 + j], b_ih_r[48 + j] + b_hh_r[48 + j]);
        const float si = __builtin_amdgcn_rcpf(1.0f + __builtin_amdgcn_exp2f(-zi * LOG2E));
        const float tg = fmaf(__builtin_amdgcn_rcpf(1.0f + __builtin_amdgcn_exp2f(-2.0f * zg * LOG2E)), 2.0f, -1.0f);
        const float so = __builtin_amdgcn_rcpf(1.0f + __builtin_amdgcn_exp2f(-zo * LOG2E));
        const float cr = si * tg;
        const float th = fmaf(__builtin_amdgcn_rcpf(1.0f + __builtin_amdgcn_exp2f(-2.0f * cr * LOG2E)), 2.0f, -1.0f);
        smem[rbase + 16 + j] = so * th;
    }
    __syncthreads();

    // ---- MLP head ----
    const int m = hl & 15;
    float hid = b1[m];
#pragma unroll
    for (int n = 0; n < 16; ++n) hid = fmaf(smem[rbase + n],      W1[m * 32 + n],      hid);
#pragma unroll
    for (int n = 0; n < 16; ++n) hid = fmaf(smem[rbase + 16 + n], W1[m * 32 + 16 + n], hid);
    hid = (hid > 0.0f) ? hid : (0.2f * hid);

    float v = hid * W2[m];
    v += __shfl_xor(v, 1);
    v += __shfl_xor(v, 2);
    v += __shfl_xor(v, 4);
    v += __shfl_xor(v, 8);
    if (hl == 0) out[b] = v + b2[0];
}

extern "C" void kernel_launch(void* const* d_in, const int* in_sizes, int n_in,
                              void* d_out, int out_size, void* d_ws, size_t ws_size,
                              hipStream_t stream) {
    const float* x      = (const float*)d_in[0];
    const float* W_ih_f = (const float*)d_in[1];
    const float* W_hh_f = (const float*)d_in[2];
    const float* b_ih_f = (const float*)d_in[3];
    const float* b_hh_f = (const float*)d_in[4];
    const float* W_ih_r = (const float*)d_in[5];
    const float* W_hh_r = (const float*)d_in[6];
    const float* b_ih_r = (const float*)d_in[7];
    const float* b_hh_r = (const float*)d_in[8];
    const float* W1     = (const float*)d_in[9];
    const float* b1     = (const float*)d_in[10];
    const float* W2     = (const float*)d_in[11];
    const float* b2     = (const float*)d_in[12];
    float* out = (float*)d_out;

    const int B = in_sizes[0] / T_LEN;   // 2048
    dim3 grid(B / 8), block(256);
    size_t lds_bytes = 8 * 560 * sizeof(float);   // 17920 B/block
    hipLaunchKernelGGL(bilstm_head_kernel, grid, block, lds_bytes, stream,
                       x, W_ih_f, W_hh_f, b_ih_f, b_hh_f,
                       W_ih_r, W_hh_r, b_ih_r, b_hh_r,
                       W1, b1, W2, b2, out);
}